// Round 1
// baseline (1422.433 us; speedup 1.0000x reference)
//
#include <hip/hip_runtime.h>

#define T_N 500000
#define NCHUNK 1024
#define CHUNKL 489   // ceil(500000/1024)
#define NPART 1024   // reduction partial blocks

__device__ __constant__ float kGAMMA = 0.99f;
__device__ __constant__ float kLAM = 0.95f;

// ---------------- fused per-row MLP kernel ----------------
// block = 128 threads (2 waves). Each lane owns one row r.
// Layer1: acc[64] in VGPRs, x via per-lane float4 global loads, W via wave-uniform (scalar) loads.
// h1 -> LDS [64][65] (own-lane only, pad kills bank conflicts), Layer2 reads it back per-k.
// Layer3s fully static-unrolled (no dynamic reg indexing).
__device__ __forceinline__ void mlp_l1(const float* __restrict__ x,
                                       const float* __restrict__ W1,
                                       const float* __restrict__ b1,
                                       float* acc)
{
    #pragma unroll
    for (int j = 0; j < 64; ++j) acc[j] = b1[j];
    #pragma unroll 2
    for (int kc = 0; kc < 128; kc += 8) {
        float4 xa = *reinterpret_cast<const float4*>(x + kc);
        float4 xb = *reinterpret_cast<const float4*>(x + kc + 4);
        float xs[8] = {xa.x, xa.y, xa.z, xa.w, xb.x, xb.y, xb.z, xb.w};
        #pragma unroll
        for (int k2 = 0; k2 < 8; ++k2) {
            const float* wr = W1 + (kc + k2) * 64;   // wave-uniform -> s_load
            float xv = xs[k2];
            #pragma unroll
            for (int j = 0; j < 64; ++j) acc[j] = fmaf(xv, wr[j], acc[j]);
        }
    }
}

__device__ __forceinline__ void mlp_l2(const float* hrow,
                                       const float* __restrict__ W2,
                                       const float* __restrict__ b2,
                                       float* acc2)
{
    #pragma unroll
    for (int j = 0; j < 64; ++j) acc2[j] = b2[j];
    #pragma unroll 4
    for (int k = 0; k < 64; ++k) {
        float hv = hrow[k];                          // LDS, conflict-free (pad 65)
        const float* wr = W2 + k * 64;               // wave-uniform -> s_load
        #pragma unroll
        for (int j = 0; j < 64; ++j) acc2[j] = fmaf(hv, wr[j], acc2[j]);
    }
}

__global__ __launch_bounds__(128) void k_mlp(
    const float* __restrict__ states, const float* __restrict__ next_states,
    const float* __restrict__ rewards, const float* __restrict__ dones,
    const int* __restrict__ actions, const float* __restrict__ old_logp,
    const float* __restrict__ aW1, const float* __restrict__ ab1,
    const float* __restrict__ aW2, const float* __restrict__ ab2,
    const float* __restrict__ aW3, const float* __restrict__ ab3,
    const float* __restrict__ cW1, const float* __restrict__ cb1,
    const float* __restrict__ cW2, const float* __restrict__ cb2,
    const float* __restrict__ cW3, const float* __restrict__ cb3,
    float* __restrict__ delta_o, float* __restrict__ coef_o,
    float* __restrict__ ratio_o, float* __restrict__ ent_o)
{
    __shared__ float hbuf[2][64][65];
    const int wv = threadIdx.x >> 6, ln = threadIdx.x & 63;
    const long long row = (long long)blockIdx.x * 128 + threadIdx.x;
    const bool valid = row < T_N;
    const long long r = valid ? row : (long long)(T_N - 1);
    float* hrow = &hbuf[wv][ln][0];

    float acc[64], acc2[64];

    // ---- critic(states) -> v ----
    mlp_l1(states + r * 128, cW1, cb1, acc);
    #pragma unroll
    for (int j = 0; j < 64; ++j) hrow[j] = fmaxf(acc[j], 0.f);
    mlp_l2(hrow, cW2, cb2, acc2);
    float v = cb3[0];
    #pragma unroll
    for (int k = 0; k < 64; ++k) v = fmaf(fmaxf(acc2[k], 0.f), cW3[k], v);

    // ---- critic(next_states) -> nv ----
    mlp_l1(next_states + r * 128, cW1, cb1, acc);
    #pragma unroll
    for (int j = 0; j < 64; ++j) hrow[j] = fmaxf(acc[j], 0.f);
    mlp_l2(hrow, cW2, cb2, acc2);
    float nv = cb3[0];
    #pragma unroll
    for (int k = 0; k < 64; ++k) nv = fmaf(fmaxf(acc2[k], 0.f), cW3[k], nv);

    // ---- actor(states) -> logits/softmax ----
    mlp_l1(states + r * 128, aW1, ab1, acc);
    #pragma unroll
    for (int j = 0; j < 64; ++j) hrow[j] = fmaxf(acc[j], 0.f);
    mlp_l2(hrow, aW2, ab2, acc2);
    float lg[16];
    #pragma unroll
    for (int a = 0; a < 16; ++a) lg[a] = ab3[a];
    #pragma unroll
    for (int k = 0; k < 64; ++k) {
        float hv = fmaxf(acc2[k], 0.f);
        #pragma unroll
        for (int a = 0; a < 16; ++a) lg[a] = fmaf(hv, aW3[k * 16 + a], lg[a]);
    }
    float m = lg[0];
    #pragma unroll
    for (int a = 1; a < 16; ++a) m = fmaxf(m, lg[a]);
    float se = 0.f;
    float p[16];
    #pragma unroll
    for (int a = 0; a < 16; ++a) { p[a] = expf(lg[a] - m); se += p[a]; }
    float inv = 1.f / se;
    float ent = 0.f;
    #pragma unroll
    for (int a = 0; a < 16; ++a) { float pr = p[a] * inv; ent -= pr * logf(pr + 1e-8f); }
    const int act = actions[r];
    float lsel = lg[0];
    #pragma unroll
    for (int a = 1; a < 16; ++a) lsel = (a == act) ? lg[a] : lsel;
    const float logp = lsel - m - logf(se);
    const float ratio = expf(logp - old_logp[r]);

    if (valid) {
        float nd = 1.f - dones[r];
        delta_o[r] = fmaf(kGAMMA * nd, nv, rewards[r]) - v;
        coef_o[r] = kGAMMA * kLAM * nd;
        ratio_o[r] = ratio;
        ent_o[r] = ent;
    }
}

// ---------------- GAE reverse scan: a_t = c_t * a_{t+1} + d_t ----------------
__global__ void k_gae_chunk(const float* __restrict__ coef, const float* __restrict__ delta,
                            float* __restrict__ P, float* __restrict__ Q)
{
    int c = blockIdx.x * blockDim.x + threadIdx.x;
    if (c >= NCHUNK) return;
    long long lo = (long long)c * CHUNKL;
    long long hi = lo + CHUNKL; if (hi > T_N) hi = T_N;
    float p = 1.f, a = 0.f;
    for (long long t = hi - 1; t >= lo; --t) {
        float ct = coef[t];
        a = fmaf(ct, a, delta[t]);
        p *= ct;
    }
    P[c] = p; Q[c] = a;
}

__global__ __launch_bounds__(1024) void k_gae_scan(const float* __restrict__ P,
                                                   const float* __restrict__ Q,
                                                   float* __restrict__ carry)
{
    __shared__ float sp[NCHUNK], sq[NCHUNK];
    int t = threadIdx.x;
    sp[t] = P[t]; sq[t] = Q[t];
    __syncthreads();
    #pragma unroll 1
    for (int d = 1; d < NCHUNK; d <<= 1) {
        float pp = sp[t], qq = sq[t];
        float p2 = 1.f, q2 = 0.f;
        bool has = (t + d) < NCHUNK;
        if (has) { p2 = sp[t + d]; q2 = sq[t + d]; }
        __syncthreads();
        if (has) { sp[t] = pp * p2; sq[t] = fmaf(pp, q2, qq); }
        __syncthreads();
    }
    carry[t] = (t + 1 < NCHUNK) ? sq[t + 1] : 0.f;
}

__global__ void k_gae_apply(const float* __restrict__ coef, const float* __restrict__ delta,
                            const float* __restrict__ carry, float* __restrict__ adv)
{
    int c = blockIdx.x * blockDim.x + threadIdx.x;
    if (c >= NCHUNK) return;
    long long lo = (long long)c * CHUNKL;
    long long hi = lo + CHUNKL; if (hi > T_N) hi = T_N;
    float a = carry[c];
    for (long long t = hi - 1; t >= lo; --t) {
        a = fmaf(coef[t], a, delta[t]);
        adv[t] = a;
    }
}

// ---------------- reductions ----------------
__global__ __launch_bounds__(256) void k_reduce_adv(const float* __restrict__ adv,
                                                    float* __restrict__ part)
{
    float s = 0.f, s2 = 0.f;
    for (long long i = (long long)blockIdx.x * 256 + threadIdx.x; i < T_N;
         i += (long long)gridDim.x * 256) {
        float a = adv[i]; s += a; s2 = fmaf(a, a, s2);
    }
    #pragma unroll
    for (int o = 32; o > 0; o >>= 1) { s += __shfl_down(s, o); s2 += __shfl_down(s2, o); }
    __shared__ float l0[4], l1[4];
    int wv = threadIdx.x >> 6, ln = threadIdx.x & 63;
    if (ln == 0) { l0[wv] = s; l1[wv] = s2; }
    __syncthreads();
    if (threadIdx.x == 0) {
        part[blockIdx.x * 2] = l0[0] + l0[1] + l0[2] + l0[3];
        part[blockIdx.x * 2 + 1] = l1[0] + l1[1] + l1[2] + l1[3];
    }
}

__global__ __launch_bounds__(1024) void k_stats(const float* __restrict__ part,
                                                float* __restrict__ stats)
{
    int t = threadIdx.x;
    float s = part[t * 2], s2 = part[t * 2 + 1];
    #pragma unroll
    for (int o = 32; o > 0; o >>= 1) { s += __shfl_down(s, o); s2 += __shfl_down(s2, o); }
    __shared__ float l0[16], l1[16];
    int wv = t >> 6, ln = t & 63;
    if (ln == 0) { l0[wv] = s; l1[wv] = s2; }
    __syncthreads();
    if (t == 0) {
        float S = 0.f, S2 = 0.f;
        #pragma unroll
        for (int i = 0; i < 16; ++i) { S += l0[i]; S2 += l1[i]; }
        const float Tf = (float)T_N;
        float mean = S / Tf;
        float var = (S2 - S * S / Tf) / (Tf - 1.f);
        float stdv = sqrtf(fmaxf(var, 0.f));
        stats[0] = mean;
        stats[1] = 1.f / (stdv + 1e-8f);
        stats[2] = S2 / Tf;   // critic_loss = mean(adv^2)
    }
}

__global__ __launch_bounds__(256) void k_actor(const float* __restrict__ adv,
                                               const float* __restrict__ ratio,
                                               const float* __restrict__ ent,
                                               const float* __restrict__ stats,
                                               float* __restrict__ part)
{
    const float mean = stats[0], isd = stats[1];
    float sm = 0.f, se = 0.f;
    for (long long i = (long long)blockIdx.x * 256 + threadIdx.x; i < T_N;
         i += (long long)gridDim.x * 256) {
        float an = (adv[i] - mean) * isd;
        float rt = ratio[i];
        float s1 = rt * an;
        float s2v = fminf(fmaxf(rt, 0.8f), 1.2f) * an;
        sm += fminf(s1, s2v);
        se += ent[i];
    }
    #pragma unroll
    for (int o = 32; o > 0; o >>= 1) { sm += __shfl_down(sm, o); se += __shfl_down(se, o); }
    __shared__ float l0[4], l1[4];
    int wv = threadIdx.x >> 6, ln = threadIdx.x & 63;
    if (ln == 0) { l0[wv] = sm; l1[wv] = se; }
    __syncthreads();
    if (threadIdx.x == 0) {
        part[blockIdx.x * 2] = l0[0] + l0[1] + l0[2] + l0[3];
        part[blockIdx.x * 2 + 1] = l1[0] + l1[1] + l1[2] + l1[3];
    }
}

__global__ __launch_bounds__(1024) void k_final(const float* __restrict__ part,
                                                const float* __restrict__ stats,
                                                float* __restrict__ out)
{
    int t = threadIdx.x;
    float sm = part[t * 2], se = part[t * 2 + 1];
    #pragma unroll
    for (int o = 32; o > 0; o >>= 1) { sm += __shfl_down(sm, o); se += __shfl_down(se, o); }
    __shared__ float l0[16], l1[16];
    int wv = t >> 6, ln = t & 63;
    if (ln == 0) { l0[wv] = sm; l1[wv] = se; }
    __syncthreads();
    if (t == 0) {
        float SM = 0.f, SE = 0.f;
        #pragma unroll
        for (int i = 0; i < 16; ++i) { SM += l0[i]; SE += l1[i]; }
        const float Tf = (float)T_N;
        float actor_loss = -SM / Tf;
        float ent_loss = SE / Tf;
        float critic_loss = stats[2];
        float total = actor_loss + 0.5f * critic_loss - 0.01f * ent_loss;
        out[0] = total; out[1] = actor_loss; out[2] = critic_loss; out[3] = ent_loss;
    }
}

extern "C" void kernel_launch(void* const* d_in, const int* in_sizes, int n_in,
                              void* d_out, int out_size, void* d_ws, size_t ws_size,
                              hipStream_t stream) {
    (void)in_sizes; (void)n_in; (void)out_size; (void)ws_size;
    const float* states      = (const float*)d_in[0];
    const float* next_states = (const float*)d_in[1];
    const float* rewards     = (const float*)d_in[2];
    const float* dones       = (const float*)d_in[3];
    const int*   actions     = (const int*)d_in[4];
    const float* old_logp    = (const float*)d_in[5];
    const float* aW1 = (const float*)d_in[6];  const float* ab1 = (const float*)d_in[7];
    const float* aW2 = (const float*)d_in[8];  const float* ab2 = (const float*)d_in[9];
    const float* aW3 = (const float*)d_in[10]; const float* ab3 = (const float*)d_in[11];
    const float* cW1 = (const float*)d_in[12]; const float* cb1 = (const float*)d_in[13];
    const float* cW2 = (const float*)d_in[14]; const float* cb2 = (const float*)d_in[15];
    const float* cW3 = (const float*)d_in[16]; const float* cb3 = (const float*)d_in[17];
    float* out = (float*)d_out;

    float* ws = (float*)d_ws;
    float* delta = ws;                 // T
    float* coef  = ws + 1 * T_N;       // T
    float* ratio = ws + 2 * T_N;       // T
    float* entb  = ws + 3 * T_N;       // T
    float* adv   = ws + 4 * T_N;       // T
    float* P     = ws + 5 * T_N;           // 1024
    float* Q     = P + NCHUNK;             // 1024
    float* carry = Q + NCHUNK;             // 1024
    float* part3 = carry + NCHUNK;         // 2048
    float* stats = part3 + 2 * NPART;      // 8
    float* part4 = stats + 8;              // 2048

    const int nblk = (T_N + 127) / 128;    // 3907
    k_mlp<<<nblk, 128, 0, stream>>>(states, next_states, rewards, dones, actions, old_logp,
                                    aW1, ab1, aW2, ab2, aW3, ab3,
                                    cW1, cb1, cW2, cb2, cW3, cb3,
                                    delta, coef, ratio, entb);
    k_gae_chunk<<<(NCHUNK + 255) / 256, 256, 0, stream>>>(coef, delta, P, Q);
    k_gae_scan<<<1, 1024, 0, stream>>>(P, Q, carry);
    k_gae_apply<<<(NCHUNK + 255) / 256, 256, 0, stream>>>(coef, delta, carry, adv);
    k_reduce_adv<<<NPART, 256, 0, stream>>>(adv, part3);
    k_stats<<<1, 1024, 0, stream>>>(part3, stats);
    k_actor<<<NPART, 256, 0, stream>>>(adv, ratio, entb, stats, part4);
    k_final<<<1, 1024, 0, stream>>>(part4, stats, out);
}

// Round 2
// 224.625 us; speedup vs baseline: 6.3325x; 6.3325x over previous
//
#include <hip/hip_runtime.h>

#define T_N 500000
#define NTILE 31250          // T_N / 16 rows per wave-tile (exact)
#define NCHUNK 4096
#define CHUNKL 128
#define NPART 1024

typedef __attribute__((ext_vector_type(8))) short short8v;
typedef __attribute__((ext_vector_type(4))) float float4v;

__device__ __forceinline__ short f2bf(float f) {
    union { float f; unsigned u; } v; v.f = f;
    unsigned r = v.u + 0x7FFFu + ((v.u >> 16) & 1u);
    return (short)(r >> 16);
}

// packed B-fragment base indices (each frag = 64 lanes x 8 bf16 = 1KB)
#define FC1 0    // critic W1: 4 k-steps x 4 col-tiles
#define FA1 16   // actor  W1
#define FC2 32   // critic W2: 2 k-steps x 4 col-tiles
#define FA2 40   // actor  W2
#define FA3 48   // actor  W3: 2 k-steps x 1 col-tile (16 actions)
#define NFRAG 50

// ---- weight pre-pack: B-frag slot (g=lane>>4, j) <-> k = s*32 + g*8 + j ----
__global__ __launch_bounds__(64) void k_pack(
    const float* __restrict__ cW1, const float* __restrict__ aW1,
    const float* __restrict__ cW2, const float* __restrict__ aW2,
    const float* __restrict__ aW3, short8v* __restrict__ packed)
{
    const int f = blockIdx.x, l = threadIdx.x;
    const int g = l >> 4, col = l & 15;
    const float* W; int s, c, ncol;
    if (f < FA1)      { W = cW1; s = f >> 2;         c = f & 3;         ncol = 64; }
    else if (f < FC2) { W = aW1; s = (f - FA1) >> 2; c = (f - FA1) & 3; ncol = 64; }
    else if (f < FA2) { W = cW2; s = (f - FC2) >> 2; c = (f - FC2) & 3; ncol = 64; }
    else if (f < FA3) { W = aW2; s = (f - FA2) >> 2; c = (f - FA2) & 3; ncol = 64; }
    else              { W = aW3; s = f - FA3;        c = 0;             ncol = 16; }
    short8v frag;
    #pragma unroll
    for (int j = 0; j < 8; ++j) {
        int k = s * 32 + g * 8 + j;
        frag[j] = f2bf(W[k * ncol + c * 16 + col]);
    }
    packed[f * 64 + l] = frag;
}

// ---- fused MLP kernel: 256 thr = 4 independent waves, 16 rows per wave ----
__global__ __launch_bounds__(256) void k_mlp(
    const float* __restrict__ states, const float* __restrict__ next_states,
    const float* __restrict__ rewards, const float* __restrict__ dones,
    const int* __restrict__ actions, const float* __restrict__ old_logp,
    const short8v* __restrict__ pk,
    const float* __restrict__ cb1, const float* __restrict__ ab1,
    const float* __restrict__ cb2, const float* __restrict__ ab2,
    const float* __restrict__ ab3,
    const float* __restrict__ cW3, const float* __restrict__ cb3,
    float* __restrict__ delta_o, float* __restrict__ coef_o,
    float* __restrict__ ratio_o, float* __restrict__ ent_o)
{
    __shared__ __align__(16) short hlds[4][16][72];   // per-wave h buffer, +8 pad
    const int wv = threadIdx.x >> 6, l = threadIdx.x & 63;
    const int g = l >> 4, q = l & 15;
    const long long tile = (long long)blockIdx.x * 4 + wv;
    if (tile >= NTILE) return;                         // no barriers in kernel
    const long long r0 = tile * 16;
    short (*h)[72] = hlds[wv];

    // ========== L1: critic(states) + actor(states) share A-frags ==========
    float4v accC[4], accA[4];
    #pragma unroll
    for (int c = 0; c < 4; ++c) {
        float b = cb1[c * 16 + q];  accC[c] = (float4v){b, b, b, b};
        float b2 = ab1[c * 16 + q]; accA[c] = (float4v){b2, b2, b2, b2};
    }
    {
        const float* xs = states + (r0 + q) * 128;
        #pragma unroll
        for (int s = 0; s < 4; ++s) {
            float4 xa = *reinterpret_cast<const float4*>(xs + s * 32 + g * 8);
            float4 xb = *reinterpret_cast<const float4*>(xs + s * 32 + g * 8 + 4);
            short8v af;
            af[0] = f2bf(xa.x); af[1] = f2bf(xa.y); af[2] = f2bf(xa.z); af[3] = f2bf(xa.w);
            af[4] = f2bf(xb.x); af[5] = f2bf(xb.y); af[6] = f2bf(xb.z); af[7] = f2bf(xb.w);
            #pragma unroll
            for (int c = 0; c < 4; ++c) {
                accC[c] = __builtin_amdgcn_mfma_f32_16x16x32_bf16(af, pk[(FC1 + s * 4 + c) * 64 + l], accC[c], 0, 0, 0);
                accA[c] = __builtin_amdgcn_mfma_f32_16x16x32_bf16(af, pk[(FA1 + s * 4 + c) * 64 + l], accA[c], 0, 0, 0);
            }
        }
    }

    // ========== critic L2 (LDS roundtrip for C-layout -> A-layout) ==========
    #pragma unroll
    for (int c = 0; c < 4; ++c)
        #pragma unroll
        for (int r = 0; r < 4; ++r)
            h[g * 4 + r][c * 16 + q] = f2bf(fmaxf(accC[c][r], 0.f));
    float4v acc2[4];
    #pragma unroll
    for (int c = 0; c < 4; ++c) { float b = cb2[c * 16 + q]; acc2[c] = (float4v){b, b, b, b}; }
    #pragma unroll
    for (int s = 0; s < 2; ++s) {
        short8v a2 = *reinterpret_cast<const short8v*>(&h[q][s * 32 + g * 8]);
        #pragma unroll
        for (int c = 0; c < 4; ++c)
            acc2[c] = __builtin_amdgcn_mfma_f32_16x16x32_bf16(a2, pk[(FC2 + s * 4 + c) * 64 + l], acc2[c], 0, 0, 0);
    }
    // critic L3 on VALU + 16-lane reduce
    float vr[4] = {0.f, 0.f, 0.f, 0.f};
    #pragma unroll
    for (int c = 0; c < 4; ++c) {
        float w = cW3[c * 16 + q];
        #pragma unroll
        for (int r = 0; r < 4; ++r) vr[r] = fmaf(fmaxf(acc2[c][r], 0.f), w, vr[r]);
    }
    #pragma unroll
    for (int o = 1; o < 16; o <<= 1)
        #pragma unroll
        for (int r = 0; r < 4; ++r) vr[r] += __shfl_xor(vr[r], o);
    const float cb3v = cb3[0];
    float v[4];
    #pragma unroll
    for (int r = 0; r < 4; ++r) v[r] = vr[r] + cb3v;

    // ========== actor L2 + L3 ==========
    #pragma unroll
    for (int c = 0; c < 4; ++c)
        #pragma unroll
        for (int r = 0; r < 4; ++r)
            h[g * 4 + r][c * 16 + q] = f2bf(fmaxf(accA[c][r], 0.f));
    float4v acc2a[4];
    #pragma unroll
    for (int c = 0; c < 4; ++c) { float b = ab2[c * 16 + q]; acc2a[c] = (float4v){b, b, b, b}; }
    #pragma unroll
    for (int s = 0; s < 2; ++s) {
        short8v a2 = *reinterpret_cast<const short8v*>(&h[q][s * 32 + g * 8]);
        #pragma unroll
        for (int c = 0; c < 4; ++c)
            acc2a[c] = __builtin_amdgcn_mfma_f32_16x16x32_bf16(a2, pk[(FA2 + s * 4 + c) * 64 + l], acc2a[c], 0, 0, 0);
    }
    #pragma unroll
    for (int c = 0; c < 4; ++c)
        #pragma unroll
        for (int r = 0; r < 4; ++r)
            h[g * 4 + r][c * 16 + q] = f2bf(fmaxf(acc2a[c][r], 0.f));
    const float b3 = ab3[q];
    float4v acc3 = (float4v){b3, b3, b3, b3};
    #pragma unroll
    for (int s = 0; s < 2; ++s) {
        short8v a3 = *reinterpret_cast<const short8v*>(&h[q][s * 32 + g * 8]);
        acc3 = __builtin_amdgcn_mfma_f32_16x16x32_bf16(a3, pk[(FA3 + s) * 64 + l], acc3, 0, 0, 0);
    }
    // softmax across the 16 lanes of the group (action = q)
    float lg[4], mx[4], pe[4], se[4], entv[4], sl[4], logp[4];
    #pragma unroll
    for (int r = 0; r < 4; ++r) { lg[r] = acc3[r]; mx[r] = lg[r]; }
    #pragma unroll
    for (int o = 1; o < 16; o <<= 1)
        #pragma unroll
        for (int r = 0; r < 4; ++r) mx[r] = fmaxf(mx[r], __shfl_xor(mx[r], o));
    #pragma unroll
    for (int r = 0; r < 4; ++r) { pe[r] = expf(lg[r] - mx[r]); se[r] = pe[r]; }
    #pragma unroll
    for (int o = 1; o < 16; o <<= 1)
        #pragma unroll
        for (int r = 0; r < 4; ++r) se[r] += __shfl_xor(se[r], o);
    #pragma unroll
    for (int r = 0; r < 4; ++r) { float pr = pe[r] / se[r]; entv[r] = -pr * logf(pr + 1e-8f); }
    #pragma unroll
    for (int o = 1; o < 16; o <<= 1)
        #pragma unroll
        for (int r = 0; r < 4; ++r) entv[r] += __shfl_xor(entv[r], o);
    const int4 av = *reinterpret_cast<const int4*>(&actions[r0 + g * 4]);
    const int act[4] = {av.x, av.y, av.z, av.w};
    #pragma unroll
    for (int r = 0; r < 4; ++r) sl[r] = (q == act[r]) ? lg[r] : -3.0e38f;
    #pragma unroll
    for (int o = 1; o < 16; o <<= 1)
        #pragma unroll
        for (int r = 0; r < 4; ++r) sl[r] = fmaxf(sl[r], __shfl_xor(sl[r], o));
    #pragma unroll
    for (int r = 0; r < 4; ++r) logp[r] = sl[r] - mx[r] - logf(se[r]);

    // ========== critic(next_states) ==========
    float4v accN[4];
    #pragma unroll
    for (int c = 0; c < 4; ++c) { float b = cb1[c * 16 + q]; accN[c] = (float4v){b, b, b, b}; }
    {
        const float* xn = next_states + (r0 + q) * 128;
        #pragma unroll
        for (int s = 0; s < 4; ++s) {
            float4 xa = *reinterpret_cast<const float4*>(xn + s * 32 + g * 8);
            float4 xb = *reinterpret_cast<const float4*>(xn + s * 32 + g * 8 + 4);
            short8v af;
            af[0] = f2bf(xa.x); af[1] = f2bf(xa.y); af[2] = f2bf(xa.z); af[3] = f2bf(xa.w);
            af[4] = f2bf(xb.x); af[5] = f2bf(xb.y); af[6] = f2bf(xb.z); af[7] = f2bf(xb.w);
            #pragma unroll
            for (int c = 0; c < 4; ++c)
                accN[c] = __builtin_amdgcn_mfma_f32_16x16x32_bf16(af, pk[(FC1 + s * 4 + c) * 64 + l], accN[c], 0, 0, 0);
        }
    }
    #pragma unroll
    for (int c = 0; c < 4; ++c)
        #pragma unroll
        for (int r = 0; r < 4; ++r)
            h[g * 4 + r][c * 16 + q] = f2bf(fmaxf(accN[c][r], 0.f));
    float4v acc2n[4];
    #pragma unroll
    for (int c = 0; c < 4; ++c) { float b = cb2[c * 16 + q]; acc2n[c] = (float4v){b, b, b, b}; }
    #pragma unroll
    for (int s = 0; s < 2; ++s) {
        short8v a2 = *reinterpret_cast<const short8v*>(&h[q][s * 32 + g * 8]);
        #pragma unroll
        for (int c = 0; c < 4; ++c)
            acc2n[c] = __builtin_amdgcn_mfma_f32_16x16x32_bf16(a2, pk[(FC2 + s * 4 + c) * 64 + l], acc2n[c], 0, 0, 0);
    }
    float nr[4] = {0.f, 0.f, 0.f, 0.f};
    #pragma unroll
    for (int c = 0; c < 4; ++c) {
        float w = cW3[c * 16 + q];
        #pragma unroll
        for (int r = 0; r < 4; ++r) nr[r] = fmaf(fmaxf(acc2n[c][r], 0.f), w, nr[r]);
    }
    #pragma unroll
    for (int o = 1; o < 16; o <<= 1)
        #pragma unroll
        for (int r = 0; r < 4; ++r) nr[r] += __shfl_xor(nr[r], o);
    float nv[4];
    #pragma unroll
    for (int r = 0; r < 4; ++r) nv[r] = nr[r] + cb3v;

    // ========== per-row outputs (lane q==0 of each group writes 4 rows) ==========
    if (q == 0) {
        const long long rb = r0 + g * 4;
        const float4 rw = *reinterpret_cast<const float4*>(&rewards[rb]);
        const float4 dn = *reinterpret_cast<const float4*>(&dones[rb]);
        const float4 ol = *reinterpret_cast<const float4*>(&old_logp[rb]);
        const float rwv[4] = {rw.x, rw.y, rw.z, rw.w};
        const float dnv[4] = {dn.x, dn.y, dn.z, dn.w};
        const float olv[4] = {ol.x, ol.y, ol.z, ol.w};
        float dl[4], cf[4], rt[4];
        const float GL = (float)(0.99 * 0.95);
        #pragma unroll
        for (int r = 0; r < 4; ++r) {
            float nd = 1.f - dnv[r];
            dl[r] = fmaf(0.99f * nd, nv[r], rwv[r]) - v[r];
            cf[r] = GL * nd;
            rt[r] = expf(logp[r] - olv[r]);
        }
        float4 t;
        t.x = dl[0]; t.y = dl[1]; t.z = dl[2]; t.w = dl[3];
        *reinterpret_cast<float4*>(&delta_o[rb]) = t;
        t.x = cf[0]; t.y = cf[1]; t.z = cf[2]; t.w = cf[3];
        *reinterpret_cast<float4*>(&coef_o[rb]) = t;
        t.x = rt[0]; t.y = rt[1]; t.z = rt[2]; t.w = rt[3];
        *reinterpret_cast<float4*>(&ratio_o[rb]) = t;
        t.x = entv[0]; t.y = entv[1]; t.z = entv[2]; t.w = entv[3];
        *reinterpret_cast<float4*>(&ent_o[rb]) = t;
    }
}

// ---------------- GAE: chunk transforms ----------------
__global__ __launch_bounds__(256) void k_gae_chunk(
    const float* __restrict__ coef, const float* __restrict__ delta,
    float* __restrict__ P, float* __restrict__ Q)
{
    const int c = blockIdx.x * 256 + threadIdx.x;
    const long long lo = (long long)c * CHUNKL;
    float p = 1.f, a = 0.f;
    if (lo < T_N) {
        const int n = (int)((T_N - lo < CHUNKL) ? (T_N - lo) : CHUNKL);
        for (int j = (n >> 2) - 1; j >= 0; --j) {
            float4 cfv = *reinterpret_cast<const float4*>(&coef[lo + 4 * j]);
            float4 dlv = *reinterpret_cast<const float4*>(&delta[lo + 4 * j]);
            a = fmaf(cfv.w, a, dlv.w);
            a = fmaf(cfv.z, a, dlv.z);
            a = fmaf(cfv.y, a, dlv.y);
            a = fmaf(cfv.x, a, dlv.x);
            p *= cfv.x * cfv.y * cfv.z * cfv.w;
        }
    }
    P[c] = p; Q[c] = a;
}

// suffix scan of 4096 chunk transforms in one block (4 per thread)
__global__ __launch_bounds__(1024) void k_gae_scan(
    const float* __restrict__ P, const float* __restrict__ Q,
    float* __restrict__ carry)
{
    __shared__ float sp[1024], sq[1024];
    const int t = threadIdx.x, b = t * 4;
    float p = P[b + 3], q = Q[b + 3];
    #pragma unroll
    for (int c = 2; c >= 0; --c) {
        float pc = P[b + c], qc = Q[b + c];
        q = fmaf(pc, q, qc);
        p = pc * p;
    }
    sp[t] = p; sq[t] = q;
    __syncthreads();
    for (int d = 1; d < 1024; d <<= 1) {
        float pp = sp[t], qq = sq[t];
        float p2 = 1.f, q2 = 0.f;
        const bool has = (t + d) < 1024;
        if (has) { p2 = sp[t + d]; q2 = sq[t + d]; }
        __syncthreads();
        if (has) { sp[t] = pp * p2; sq[t] = fmaf(pp, q2, qq); }
        __syncthreads();
    }
    float x = (t + 1 < 1024) ? sq[t + 1] : 0.f;
    #pragma unroll
    for (int c = 3; c >= 0; --c) {
        carry[b + c] = x;
        x = fmaf(P[b + c], x, Q[b + c]);
    }
}

// apply carries, write adv, fused sum/sum^2 partials
__global__ __launch_bounds__(256) void k_gae_apply(
    const float* __restrict__ coef, const float* __restrict__ delta,
    const float* __restrict__ carry, float* __restrict__ adv,
    float* __restrict__ part)
{
    const int c = blockIdx.x * 256 + threadIdx.x;
    const long long lo = (long long)c * CHUNKL;
    float s = 0.f, s2 = 0.f;
    if (lo < T_N) {
        const int n = (int)((T_N - lo < CHUNKL) ? (T_N - lo) : CHUNKL);
        float a = carry[c];
        for (int j = (n >> 2) - 1; j >= 0; --j) {
            float4 cfv = *reinterpret_cast<const float4*>(&coef[lo + 4 * j]);
            float4 dlv = *reinterpret_cast<const float4*>(&delta[lo + 4 * j]);
            float a3 = fmaf(cfv.w, a, dlv.w);
            float a2v = fmaf(cfv.z, a3, dlv.z);
            float a1 = fmaf(cfv.y, a2v, dlv.y);
            float a0 = fmaf(cfv.x, a1, dlv.x);
            float4 o; o.x = a0; o.y = a1; o.z = a2v; o.w = a3;
            *reinterpret_cast<float4*>(&adv[lo + 4 * j]) = o;
            a = a0;
            s += a0 + a1 + a2v + a3;
            s2 += a0 * a0 + a1 * a1 + a2v * a2v + a3 * a3;
        }
    }
    #pragma unroll
    for (int o = 32; o > 0; o >>= 1) { s += __shfl_down(s, o); s2 += __shfl_down(s2, o); }
    __shared__ float l0[4], l1[4];
    const int wv = threadIdx.x >> 6, ln = threadIdx.x & 63;
    if (ln == 0) { l0[wv] = s; l1[wv] = s2; }
    __syncthreads();
    if (threadIdx.x == 0) {
        part[blockIdx.x * 2]     = l0[0] + l0[1] + l0[2] + l0[3];
        part[blockIdx.x * 2 + 1] = l1[0] + l1[1] + l1[2] + l1[3];
    }
}

// actor surrogate + entropy reduction
__global__ __launch_bounds__(256) void k_actor(
    const float* __restrict__ adv, const float* __restrict__ ratio,
    const float* __restrict__ ent, const float* __restrict__ part,
    float* __restrict__ part4)
{
    __shared__ float st[2];
    if (threadIdx.x == 0) {
        float S = 0.f, S2 = 0.f;
        #pragma unroll
        for (int i = 0; i < 16; ++i) { S += part[2 * i]; S2 += part[2 * i + 1]; }
        const float Tf = (float)T_N;
        float mean = S / Tf;
        float var = (S2 - S * S / Tf) / (Tf - 1.f);
        st[0] = mean;
        st[1] = 1.f / (sqrtf(fmaxf(var, 0.f)) + 1e-8f);
    }
    __syncthreads();
    const float mean = st[0], isd = st[1];
    float sm = 0.f, se = 0.f;
    for (long long i = (long long)blockIdx.x * 256 + threadIdx.x; i < T_N;
         i += (long long)gridDim.x * 256) {
        float an = (adv[i] - mean) * isd;
        float rt = ratio[i];
        float s1 = rt * an;
        float s2v = fminf(fmaxf(rt, 0.8f), 1.2f) * an;
        sm += fminf(s1, s2v);
        se += ent[i];
    }
    #pragma unroll
    for (int o = 32; o > 0; o >>= 1) { sm += __shfl_down(sm, o); se += __shfl_down(se, o); }
    __shared__ float l0[4], l1[4];
    const int wv = threadIdx.x >> 6, ln = threadIdx.x & 63;
    if (ln == 0) { l0[wv] = sm; l1[wv] = se; }
    __syncthreads();
    if (threadIdx.x == 0) {
        part4[blockIdx.x * 2]     = l0[0] + l0[1] + l0[2] + l0[3];
        part4[blockIdx.x * 2 + 1] = l1[0] + l1[1] + l1[2] + l1[3];
    }
}

__global__ __launch_bounds__(1024) void k_final(
    const float* __restrict__ part4, const float* __restrict__ part,
    float* __restrict__ out)
{
    const int t = threadIdx.x;
    float sm = part4[t * 2], se = part4[t * 2 + 1];
    #pragma unroll
    for (int o = 32; o > 0; o >>= 1) { sm += __shfl_down(sm, o); se += __shfl_down(se, o); }
    __shared__ float l0[16], l1[16];
    const int wv = t >> 6, ln = t & 63;
    if (ln == 0) { l0[wv] = sm; l1[wv] = se; }
    __syncthreads();
    if (t == 0) {
        float SM = 0.f, SE = 0.f;
        #pragma unroll
        for (int i = 0; i < 16; ++i) { SM += l0[i]; SE += l1[i]; }
        float S2 = 0.f;
        #pragma unroll
        for (int i = 0; i < 16; ++i) S2 += part[2 * i + 1];
        const float Tf = (float)T_N;
        float actor_loss = -SM / Tf;
        float ent_loss = SE / Tf;
        float critic_loss = S2 / Tf;     // mean(adv^2) == mean((v-returns)^2)
        float total = actor_loss + 0.5f * critic_loss - 0.01f * ent_loss;
        out[0] = total; out[1] = actor_loss; out[2] = critic_loss; out[3] = ent_loss;
    }
}

extern "C" void kernel_launch(void* const* d_in, const int* in_sizes, int n_in,
                              void* d_out, int out_size, void* d_ws, size_t ws_size,
                              hipStream_t stream) {
    (void)in_sizes; (void)n_in; (void)out_size; (void)ws_size;
    const float* states      = (const float*)d_in[0];
    const float* next_states = (const float*)d_in[1];
    const float* rewards     = (const float*)d_in[2];
    const float* dones       = (const float*)d_in[3];
    const int*   actions     = (const int*)d_in[4];
    const float* old_logp    = (const float*)d_in[5];
    const float* aW1 = (const float*)d_in[6];  const float* ab1 = (const float*)d_in[7];
    const float* aW2 = (const float*)d_in[8];  const float* ab2 = (const float*)d_in[9];
    const float* aW3 = (const float*)d_in[10]; const float* ab3 = (const float*)d_in[11];
    const float* cW1 = (const float*)d_in[12]; const float* cb1 = (const float*)d_in[13];
    const float* cW2 = (const float*)d_in[14]; const float* cb2 = (const float*)d_in[15];
    const float* cW3 = (const float*)d_in[16]; const float* cb3 = (const float*)d_in[17];
    float* out = (float*)d_out;

    float* ws = (float*)d_ws;
    float* delta = ws;                      // T
    float* coef  = ws + 1 * (size_t)T_N;    // T
    float* ratio = ws + 2 * (size_t)T_N;    // T
    float* entb  = ws + 3 * (size_t)T_N;    // T
    float* adv   = ws + 4 * (size_t)T_N;    // T
    float* P     = ws + 5 * (size_t)T_N;    // 4096
    float* Q     = P + NCHUNK;              // 4096
    float* carry = Q + NCHUNK;              // 4096
    float* part  = carry + NCHUNK;          // 32
    float* part4 = part + 32;               // 2048
    short8v* packed = (short8v*)(part4 + 2048);  // 50KB, 16B-aligned offset

    k_pack<<<NFRAG, 64, 0, stream>>>(cW1, aW1, cW2, aW2, aW3, packed);
    k_mlp<<<(NTILE + 3) / 4, 256, 0, stream>>>(
        states, next_states, rewards, dones, actions, old_logp, packed,
        cb1, ab1, cb2, ab2, ab3, cW3, cb3, delta, coef, ratio, entb);
    k_gae_chunk<<<NCHUNK / 256, 256, 0, stream>>>(coef, delta, P, Q);
    k_gae_scan<<<1, 1024, 0, stream>>>(P, Q, carry);
    k_gae_apply<<<NCHUNK / 256, 256, 0, stream>>>(coef, delta, carry, adv, part);
    k_actor<<<NPART, 256, 0, stream>>>(adv, ratio, entb, part, part4);
    k_final<<<1, 1024, 0, stream>>>(part4, part, out);
}

// Round 3
// 213.534 us; speedup vs baseline: 6.6614x; 1.0519x over previous
//
#include <hip/hip_runtime.h>
#include <hip/hip_bf16.h>

#define T_N 500000
#define NTILE2 15625         // T_N / 32 rows per wave (exact)
#define NCHUNK 4096
#define CHUNKL 128
#define NPART 1024

typedef __attribute__((ext_vector_type(8))) short short8v;
typedef __attribute__((ext_vector_type(4))) float float4v;

__device__ __forceinline__ short f2bf(float f) {
    __hip_bfloat16 b = __float2bfloat16(f);
    return *reinterpret_cast<short*>(&b);
}

// packed B-fragment base indices (each frag = 64 lanes x 8 bf16 = 1KB)
#define FC1 0    // critic W1: 4 k-steps x 4 col-tiles
#define FA1 16   // actor  W1
#define FC2 32   // critic W2: 2 k-steps x 4 col-tiles
#define FA2 40   // actor  W2
#define FA3 48   // actor  W3: 2 k-steps x 1 col-tile (16 actions)
#define NFRAG 50

// ---- weight pre-pack: B-frag slot (g=lane>>4, j) <-> k = s*32 + g*8 + j ----
__global__ __launch_bounds__(64) void k_pack(
    const float* __restrict__ cW1, const float* __restrict__ aW1,
    const float* __restrict__ cW2, const float* __restrict__ aW2,
    const float* __restrict__ aW3, short8v* __restrict__ packed)
{
    const int f = blockIdx.x, l = threadIdx.x;
    const int g = l >> 4, col = l & 15;
    const float* W; int s, c, ncol;
    if (f < FA1)      { W = cW1; s = f >> 2;         c = f & 3;         ncol = 64; }
    else if (f < FC2) { W = aW1; s = (f - FA1) >> 2; c = (f - FA1) & 3; ncol = 64; }
    else if (f < FA2) { W = cW2; s = (f - FC2) >> 2; c = (f - FC2) & 3; ncol = 64; }
    else if (f < FA3) { W = aW2; s = (f - FA2) >> 2; c = (f - FA2) & 3; ncol = 64; }
    else              { W = aW3; s = f - FA3;        c = 0;             ncol = 16; }
    short8v frag;
    #pragma unroll
    for (int j = 0; j < 8; ++j) {
        int k = s * 32 + g * 8 + j;
        frag[j] = f2bf(W[k * ncol + c * 16 + col]);
    }
    packed[f * 64 + l] = frag;
}

__device__ __forceinline__ short8v pack_afrag(const float* __restrict__ xrow, int off) {
    float4 xa = *reinterpret_cast<const float4*>(xrow + off);
    float4 xb = *reinterpret_cast<const float4*>(xrow + off + 4);
    short8v af;
    af[0] = f2bf(xa.x); af[1] = f2bf(xa.y); af[2] = f2bf(xa.z); af[3] = f2bf(xa.w);
    af[4] = f2bf(xb.x); af[5] = f2bf(xb.y); af[6] = f2bf(xb.z); af[7] = f2bf(xb.w);
    return af;
}

__device__ __forceinline__ void store_h(short (*hb)[68], const float4v* acc, int g, int q) {
    #pragma unroll
    for (int c = 0; c < 4; ++c)
        #pragma unroll
        for (int r = 0; r < 4; ++r)
            hb[g * 4 + r][c * 16 + q] = f2bf(fmaxf(acc[c][r], 0.f));
}

// L2 critic + L3 head for one 16-row h buffer -> v[4] (all lanes hold result)
__device__ __forceinline__ void l2_critic(const short* hbase, const short8v* fc2,
                                          const float* bc2, const float* w3, float cb3v,
                                          int g, int q, float* vout)
{
    float4v acc[4];
    #pragma unroll
    for (int c = 0; c < 4; ++c) acc[c] = (float4v){bc2[c], bc2[c], bc2[c], bc2[c]};
    #pragma unroll
    for (int s = 0; s < 2; ++s) {
        short8v a2 = *reinterpret_cast<const short8v*>(hbase + q * 68 + s * 32 + g * 8);
        #pragma unroll
        for (int c = 0; c < 4; ++c)
            acc[c] = __builtin_amdgcn_mfma_f32_16x16x32_bf16(a2, fc2[s * 4 + c], acc[c], 0, 0, 0);
    }
    float vr[4] = {0.f, 0.f, 0.f, 0.f};
    #pragma unroll
    for (int c = 0; c < 4; ++c)
        #pragma unroll
        for (int r = 0; r < 4; ++r) vr[r] = fmaf(fmaxf(acc[c][r], 0.f), w3[c], vr[r]);
    #pragma unroll
    for (int o = 1; o < 16; o <<= 1)
        #pragma unroll
        for (int r = 0; r < 4; ++r) vr[r] += __shfl_xor(vr[r], o);
    #pragma unroll
    for (int r = 0; r < 4; ++r) vout[r] = vr[r] + cb3v;
}

// actor L2+L3+softmax for one 16-row sub-tile -> logp[4], ent[4]
__device__ __forceinline__ void actor_head(const short* h_in, short (*h_tmp)[68],
                                           const short8v* fa2, const short8v* fa3,
                                           const float* ba2, float ab3q,
                                           int g, int q, long long r0s,
                                           const int* __restrict__ actions,
                                           float* logp, float* entv)
{
    float4v acc[4];
    #pragma unroll
    for (int c = 0; c < 4; ++c) acc[c] = (float4v){ba2[c], ba2[c], ba2[c], ba2[c]};
    #pragma unroll
    for (int s = 0; s < 2; ++s) {
        short8v a2 = *reinterpret_cast<const short8v*>(h_in + q * 68 + s * 32 + g * 8);
        #pragma unroll
        for (int c = 0; c < 4; ++c)
            acc[c] = __builtin_amdgcn_mfma_f32_16x16x32_bf16(a2, fa2[s * 4 + c], acc[c], 0, 0, 0);
    }
    store_h(h_tmp, acc, g, q);
    float4v acc3 = (float4v){ab3q, ab3q, ab3q, ab3q};
    #pragma unroll
    for (int s = 0; s < 2; ++s) {
        short8v a3 = *reinterpret_cast<const short8v*>(&h_tmp[q][s * 32 + g * 8]);
        acc3 = __builtin_amdgcn_mfma_f32_16x16x32_bf16(a3, fa3[s], acc3, 0, 0, 0);
    }
    float lg[4], mx[4], pe[4], se[4], sl[4];
    #pragma unroll
    for (int r = 0; r < 4; ++r) { lg[r] = acc3[r]; mx[r] = lg[r]; }
    #pragma unroll
    for (int o = 1; o < 16; o <<= 1)
        #pragma unroll
        for (int r = 0; r < 4; ++r) mx[r] = fmaxf(mx[r], __shfl_xor(mx[r], o));
    #pragma unroll
    for (int r = 0; r < 4; ++r) { pe[r] = expf(lg[r] - mx[r]); se[r] = pe[r]; }
    #pragma unroll
    for (int o = 1; o < 16; o <<= 1)
        #pragma unroll
        for (int r = 0; r < 4; ++r) se[r] += __shfl_xor(se[r], o);
    #pragma unroll
    for (int r = 0; r < 4; ++r) { float pr = pe[r] / se[r]; entv[r] = -pr * logf(pr + 1e-8f); }
    #pragma unroll
    for (int o = 1; o < 16; o <<= 1)
        #pragma unroll
        for (int r = 0; r < 4; ++r) entv[r] += __shfl_xor(entv[r], o);
    const int4 av = *reinterpret_cast<const int4*>(&actions[r0s + g * 4]);
    const int act[4] = {av.x, av.y, av.z, av.w};
    #pragma unroll
    for (int r = 0; r < 4; ++r) sl[r] = (q == act[r]) ? lg[r] : -3.0e38f;
    #pragma unroll
    for (int o = 1; o < 16; o <<= 1)
        #pragma unroll
        for (int r = 0; r < 4; ++r) sl[r] = fmaxf(sl[r], __shfl_xor(sl[r], o));
    #pragma unroll
    for (int r = 0; r < 4; ++r) logp[r] = sl[r] - mx[r] - logf(se[r]);
}

// ---- fused MLP: 4 waves/block, 32 rows (2 sub-tiles) per wave, no barriers ----
__global__ __launch_bounds__(256) void k_mlp(
    const float* __restrict__ states, const float* __restrict__ next_states,
    const float* __restrict__ rewards, const float* __restrict__ dones,
    const int* __restrict__ actions, const float* __restrict__ old_logp,
    const short8v* __restrict__ pk,
    const float* __restrict__ cb1, const float* __restrict__ ab1,
    const float* __restrict__ cb2, const float* __restrict__ ab2,
    const float* __restrict__ ab3,
    const float* __restrict__ cW3, const float* __restrict__ cb3,
    float* __restrict__ delta_o, float* __restrict__ coef_o,
    float* __restrict__ ratio_o, float* __restrict__ ent_o)
{
    __shared__ __align__(16) short hlds[4][4][16][68];
    const int wv = threadIdx.x >> 6, l = threadIdx.x & 63;
    const int g = l >> 4, q = l & 15;
    const int tile = blockIdx.x * 4 + wv;
    if (tile >= NTILE2) return;
    const long long r0 = (long long)tile * 32;
    short (*hb0)[68] = hlds[wv][0];
    short (*hb1)[68] = hlds[wv][1];
    short (*hb2)[68] = hlds[wv][2];
    short (*hb3)[68] = hlds[wv][3];

    // ================= Phase A: critic L1 (states x2, next x2) =================
    float bc1[4];
    #pragma unroll
    for (int c = 0; c < 4; ++c) bc1[c] = cb1[c * 16 + q];
    short8v fc1[16];
    #pragma unroll
    for (int f = 0; f < 16; ++f) fc1[f] = pk[(FC1 + f) * 64 + l];

    const float* xs0 = states + (r0 + q) * 128;
    const float* xs1 = xs0 + 16 * 128;
    short8v sa0[4], sa1[4];
    #pragma unroll
    for (int s = 0; s < 4; ++s) {
        sa0[s] = pack_afrag(xs0, s * 32 + g * 8);
        sa1[s] = pack_afrag(xs1, s * 32 + g * 8);
    }
    {
        float4v aC0[4], aC1[4];
        #pragma unroll
        for (int c = 0; c < 4; ++c) {
            aC0[c] = (float4v){bc1[c], bc1[c], bc1[c], bc1[c]};
            aC1[c] = aC0[c];
        }
        #pragma unroll
        for (int s = 0; s < 4; ++s)
            #pragma unroll
            for (int c = 0; c < 4; ++c) {
                aC0[c] = __builtin_amdgcn_mfma_f32_16x16x32_bf16(sa0[s], fc1[s * 4 + c], aC0[c], 0, 0, 0);
                aC1[c] = __builtin_amdgcn_mfma_f32_16x16x32_bf16(sa1[s], fc1[s * 4 + c], aC1[c], 0, 0, 0);
            }
        store_h(hb0, aC0, g, q);
        store_h(hb1, aC1, g, q);
    }
    {
        const float* xn0 = next_states + (r0 + q) * 128;
        short8v na[4];
        #pragma unroll
        for (int s = 0; s < 4; ++s) na[s] = pack_afrag(xn0, s * 32 + g * 8);
        float4v aN[4];
        #pragma unroll
        for (int c = 0; c < 4; ++c) aN[c] = (float4v){bc1[c], bc1[c], bc1[c], bc1[c]};
        #pragma unroll
        for (int s = 0; s < 4; ++s)
            #pragma unroll
            for (int c = 0; c < 4; ++c)
                aN[c] = __builtin_amdgcn_mfma_f32_16x16x32_bf16(na[s], fc1[s * 4 + c], aN[c], 0, 0, 0);
        store_h(hb2, aN, g, q);
        const float* xn1 = xn0 + 16 * 128;
        #pragma unroll
        for (int s = 0; s < 4; ++s) na[s] = pack_afrag(xn1, s * 32 + g * 8);
        #pragma unroll
        for (int c = 0; c < 4; ++c) aN[c] = (float4v){bc1[c], bc1[c], bc1[c], bc1[c]};
        #pragma unroll
        for (int s = 0; s < 4; ++s)
            #pragma unroll
            for (int c = 0; c < 4; ++c)
                aN[c] = __builtin_amdgcn_mfma_f32_16x16x32_bf16(na[s], fc1[s * 4 + c], aN[c], 0, 0, 0);
        store_h(hb3, aN, g, q);
    }

    // ================= Phase B: critic L2 + head for 4 buffers =================
    float v0[4], v1[4], nv0[4], nv1[4];
    {
        short8v fc2[8];
        #pragma unroll
        for (int f = 0; f < 8; ++f) fc2[f] = pk[(FC2 + f) * 64 + l];
        float bc2[4], w3[4];
        #pragma unroll
        for (int c = 0; c < 4; ++c) { bc2[c] = cb2[c * 16 + q]; w3[c] = cW3[c * 16 + q]; }
        const float cb3v = cb3[0];
        l2_critic(&hb0[0][0], fc2, bc2, w3, cb3v, g, q, v0);
        l2_critic(&hb1[0][0], fc2, bc2, w3, cb3v, g, q, v1);
        l2_critic(&hb2[0][0], fc2, bc2, w3, cb3v, g, q, nv0);
        l2_critic(&hb3[0][0], fc2, bc2, w3, cb3v, g, q, nv1);
    }

    // ================= Phase C: actor L1 (states x2, reuse sa frags) ===========
    {
        float ba1[4];
        #pragma unroll
        for (int c = 0; c < 4; ++c) ba1[c] = ab1[c * 16 + q];
        short8v fa1[16];
        #pragma unroll
        for (int f = 0; f < 16; ++f) fa1[f] = pk[(FA1 + f) * 64 + l];
        float4v aA0[4], aA1[4];
        #pragma unroll
        for (int c = 0; c < 4; ++c) {
            aA0[c] = (float4v){ba1[c], ba1[c], ba1[c], ba1[c]};
            aA1[c] = aA0[c];
        }
        #pragma unroll
        for (int s = 0; s < 4; ++s)
            #pragma unroll
            for (int c = 0; c < 4; ++c) {
                aA0[c] = __builtin_amdgcn_mfma_f32_16x16x32_bf16(sa0[s], fa1[s * 4 + c], aA0[c], 0, 0, 0);
                aA1[c] = __builtin_amdgcn_mfma_f32_16x16x32_bf16(sa1[s], fa1[s * 4 + c], aA1[c], 0, 0, 0);
            }
        store_h(hb0, aA0, g, q);
        store_h(hb1, aA1, g, q);
    }

    // ================= Phase D: actor L2 + L3 + softmax =================
    float logp0[4], ent0[4], logp1[4], ent1[4];
    {
        short8v fa2[8], fa3[2];
        #pragma unroll
        for (int f = 0; f < 8; ++f) fa2[f] = pk[(FA2 + f) * 64 + l];
        fa3[0] = pk[(FA3 + 0) * 64 + l];
        fa3[1] = pk[(FA3 + 1) * 64 + l];
        float ba2[4];
        #pragma unroll
        for (int c = 0; c < 4; ++c) ba2[c] = ab2[c * 16 + q];
        const float ab3q = ab3[q];
        actor_head(&hb0[0][0], hb2, fa2, fa3, ba2, ab3q, g, q, r0,      actions, logp0, ent0);
        actor_head(&hb1[0][0], hb3, fa2, fa3, ba2, ab3q, g, q, r0 + 16, actions, logp1, ent1);
    }

    // ================= Epilogue =================
    if (q == 0) {
        const float GL = 0.99f * 0.95f;
        #pragma unroll
        for (int sub = 0; sub < 2; ++sub) {
            const long long rb = r0 + sub * 16 + g * 4;
            const float* vv = sub ? v1 : v0;
            const float* nn = sub ? nv1 : nv0;
            const float* lp = sub ? logp1 : logp0;
            const float* ev = sub ? ent1 : ent0;
            const float4 rw = *reinterpret_cast<const float4*>(&rewards[rb]);
            const float4 dn = *reinterpret_cast<const float4*>(&dones[rb]);
            const float4 ol = *reinterpret_cast<const float4*>(&old_logp[rb]);
            const float rwv[4] = {rw.x, rw.y, rw.z, rw.w};
            const float dnv[4] = {dn.x, dn.y, dn.z, dn.w};
            const float olv[4] = {ol.x, ol.y, ol.z, ol.w};
            float dl[4], cf[4], rt[4];
            #pragma unroll
            for (int r = 0; r < 4; ++r) {
                float nd = 1.f - dnv[r];
                dl[r] = fmaf(0.99f * nd, nn[r], rwv[r]) - vv[r];
                cf[r] = GL * nd;
                rt[r] = expf(lp[r] - olv[r]);
            }
            float4 t;
            t.x = dl[0]; t.y = dl[1]; t.z = dl[2]; t.w = dl[3];
            *reinterpret_cast<float4*>(&delta_o[rb]) = t;
            t.x = cf[0]; t.y = cf[1]; t.z = cf[2]; t.w = cf[3];
            *reinterpret_cast<float4*>(&coef_o[rb]) = t;
            t.x = rt[0]; t.y = rt[1]; t.z = rt[2]; t.w = rt[3];
            *reinterpret_cast<float4*>(&ratio_o[rb]) = t;
            t.x = ev[0]; t.y = ev[1]; t.z = ev[2]; t.w = ev[3];
            *reinterpret_cast<float4*>(&ent_o[rb]) = t;
        }
    }
}

// ---------------- GAE: chunk transforms ----------------
__global__ __launch_bounds__(256) void k_gae_chunk(
    const float* __restrict__ coef, const float* __restrict__ delta,
    float* __restrict__ P, float* __restrict__ Q)
{
    const int c = blockIdx.x * 256 + threadIdx.x;
    const long long lo = (long long)c * CHUNKL;
    float p = 1.f, a = 0.f;
    if (lo < T_N) {
        const int n = (int)((T_N - lo < CHUNKL) ? (T_N - lo) : CHUNKL);
        for (int j = (n >> 2) - 1; j >= 0; --j) {
            float4 cfv = *reinterpret_cast<const float4*>(&coef[lo + 4 * j]);
            float4 dlv = *reinterpret_cast<const float4*>(&delta[lo + 4 * j]);
            a = fmaf(cfv.w, a, dlv.w);
            a = fmaf(cfv.z, a, dlv.z);
            a = fmaf(cfv.y, a, dlv.y);
            a = fmaf(cfv.x, a, dlv.x);
            p *= cfv.x * cfv.y * cfv.z * cfv.w;
        }
    }
    P[c] = p; Q[c] = a;
}

// suffix scan of 4096 chunk transforms in one block (4 per thread)
__global__ __launch_bounds__(1024) void k_gae_scan(
    const float* __restrict__ P, const float* __restrict__ Q,
    float* __restrict__ carry)
{
    __shared__ float sp[1024], sq[1024];
    const int t = threadIdx.x, b = t * 4;
    float p = P[b + 3], q = Q[b + 3];
    #pragma unroll
    for (int c = 2; c >= 0; --c) {
        float pc = P[b + c], qc = Q[b + c];
        q = fmaf(pc, q, qc);
        p = pc * p;
    }
    sp[t] = p; sq[t] = q;
    __syncthreads();
    for (int d = 1; d < 1024; d <<= 1) {
        float pp = sp[t], qq = sq[t];
        float p2 = 1.f, q2 = 0.f;
        const bool has = (t + d) < 1024;
        if (has) { p2 = sp[t + d]; q2 = sq[t + d]; }
        __syncthreads();
        if (has) { sp[t] = pp * p2; sq[t] = fmaf(pp, q2, qq); }
        __syncthreads();
    }
    float x = (t + 1 < 1024) ? sq[t + 1] : 0.f;
    #pragma unroll
    for (int c = 3; c >= 0; --c) {
        carry[b + c] = x;
        x = fmaf(P[b + c], x, Q[b + c]);
    }
}

// apply carries, write adv, fused sum/sum^2 partials
__global__ __launch_bounds__(256) void k_gae_apply(
    const float* __restrict__ coef, const float* __restrict__ delta,
    const float* __restrict__ carry, float* __restrict__ adv,
    float* __restrict__ part)
{
    const int c = blockIdx.x * 256 + threadIdx.x;
    const long long lo = (long long)c * CHUNKL;
    float s = 0.f, s2 = 0.f;
    if (lo < T_N) {
        const int n = (int)((T_N - lo < CHUNKL) ? (T_N - lo) : CHUNKL);
        float a = carry[c];
        for (int j = (n >> 2) - 1; j >= 0; --j) {
            float4 cfv = *reinterpret_cast<const float4*>(&coef[lo + 4 * j]);
            float4 dlv = *reinterpret_cast<const float4*>(&delta[lo + 4 * j]);
            float a3 = fmaf(cfv.w, a, dlv.w);
            float a2v = fmaf(cfv.z, a3, dlv.z);
            float a1 = fmaf(cfv.y, a2v, dlv.y);
            float a0 = fmaf(cfv.x, a1, dlv.x);
            float4 o; o.x = a0; o.y = a1; o.z = a2v; o.w = a3;
            *reinterpret_cast<float4*>(&adv[lo + 4 * j]) = o;
            a = a0;
            s += a0 + a1 + a2v + a3;
            s2 += a0 * a0 + a1 * a1 + a2v * a2v + a3 * a3;
        }
    }
    #pragma unroll
    for (int o = 32; o > 0; o >>= 1) { s += __shfl_down(s, o); s2 += __shfl_down(s2, o); }
    __shared__ float l0[4], l1[4];
    const int wv = threadIdx.x >> 6, ln = threadIdx.x & 63;
    if (ln == 0) { l0[wv] = s; l1[wv] = s2; }
    __syncthreads();
    if (threadIdx.x == 0) {
        part[blockIdx.x * 2]     = l0[0] + l0[1] + l0[2] + l0[3];
        part[blockIdx.x * 2 + 1] = l1[0] + l1[1] + l1[2] + l1[3];
    }
}

// actor surrogate + entropy reduction
__global__ __launch_bounds__(256) void k_actor(
    const float* __restrict__ adv, const float* __restrict__ ratio,
    const float* __restrict__ ent, const float* __restrict__ part,
    float* __restrict__ part4)
{
    __shared__ float st[2];
    if (threadIdx.x == 0) {
        float S = 0.f, S2 = 0.f;
        #pragma unroll
        for (int i = 0; i < 16; ++i) { S += part[2 * i]; S2 += part[2 * i + 1]; }
        const float Tf = (float)T_N;
        float mean = S / Tf;
        float var = (S2 - S * S / Tf) / (Tf - 1.f);
        st[0] = mean;
        st[1] = 1.f / (sqrtf(fmaxf(var, 0.f)) + 1e-8f);
    }
    __syncthreads();
    const float mean = st[0], isd = st[1];
    float sm = 0.f, se = 0.f;
    for (long long i = (long long)blockIdx.x * 256 + threadIdx.x; i < T_N;
         i += (long long)gridDim.x * 256) {
        float an = (adv[i] - mean) * isd;
        float rt = ratio[i];
        float s1 = rt * an;
        float s2v = fminf(fmaxf(rt, 0.8f), 1.2f) * an;
        sm += fminf(s1, s2v);
        se += ent[i];
    }
    #pragma unroll
    for (int o = 32; o > 0; o >>= 1) { sm += __shfl_down(sm, o); se += __shfl_down(se, o); }
    __shared__ float l0[4], l1[4];
    const int wv = threadIdx.x >> 6, ln = threadIdx.x & 63;
    if (ln == 0) { l0[wv] = sm; l1[wv] = se; }
    __syncthreads();
    if (threadIdx.x == 0) {
        part4[blockIdx.x * 2]     = l0[0] + l0[1] + l0[2] + l0[3];
        part4[blockIdx.x * 2 + 1] = l1[0] + l1[1] + l1[2] + l1[3];
    }
}

__global__ __launch_bounds__(1024) void k_final(
    const float* __restrict__ part4, const float* __restrict__ part,
    float* __restrict__ out)
{
    const int t = threadIdx.x;
    float sm = part4[t * 2], se = part4[t * 2 + 1];
    #pragma unroll
    for (int o = 32; o > 0; o >>= 1) { sm += __shfl_down(sm, o); se += __shfl_down(se, o); }
    __shared__ float l0[16], l1[16];
    const int wv = t >> 6, ln = t & 63;
    if (ln == 0) { l0[wv] = sm; l1[wv] = se; }
    __syncthreads();
    if (t == 0) {
        float SM = 0.f, SE = 0.f;
        #pragma unroll
        for (int i = 0; i < 16; ++i) { SM += l0[i]; SE += l1[i]; }
        float S2 = 0.f;
        #pragma unroll
        for (int i = 0; i < 16; ++i) S2 += part[2 * i + 1];
        const float Tf = (float)T_N;
        float actor_loss = -SM / Tf;
        float ent_loss = SE / Tf;
        float critic_loss = S2 / Tf;     // mean(adv^2) == mean((v-returns)^2)
        float total = actor_loss + 0.5f * critic_loss - 0.01f * ent_loss;
        out[0] = total; out[1] = actor_loss; out[2] = critic_loss; out[3] = ent_loss;
    }
}

extern "C" void kernel_launch(void* const* d_in, const int* in_sizes, int n_in,
                              void* d_out, int out_size, void* d_ws, size_t ws_size,
                              hipStream_t stream) {
    (void)in_sizes; (void)n_in; (void)out_size; (void)ws_size;
    const float* states      = (const float*)d_in[0];
    const float* next_states = (const float*)d_in[1];
    const float* rewards     = (const float*)d_in[2];
    const float* dones       = (const float*)d_in[3];
    const int*   actions     = (const int*)d_in[4];
    const float* old_logp    = (const float*)d_in[5];
    const float* aW1 = (const float*)d_in[6];  const float* ab1 = (const float*)d_in[7];
    const float* aW2 = (const float*)d_in[8];  const float* ab2 = (const float*)d_in[9];
    const float* aW3 = (const float*)d_in[10]; const float* ab3 = (const float*)d_in[11];
    const float* cW1 = (const float*)d_in[12]; const float* cb1 = (const float*)d_in[13];
    const float* cW2 = (const float*)d_in[14]; const float* cb2 = (const float*)d_in[15];
    const float* cW3 = (const float*)d_in[16]; const float* cb3 = (const float*)d_in[17];
    float* out = (float*)d_out;

    float* ws = (float*)d_ws;
    float* delta = ws;                      // T
    float* coef  = ws + 1 * (size_t)T_N;    // T
    float* ratio = ws + 2 * (size_t)T_N;    // T
    float* entb  = ws + 3 * (size_t)T_N;    // T
    float* adv   = ws + 4 * (size_t)T_N;    // T
    float* P     = ws + 5 * (size_t)T_N;    // 4096
    float* Q     = P + NCHUNK;              // 4096
    float* carry = Q + NCHUNK;              // 4096
    float* part  = carry + NCHUNK;          // 32
    float* part4 = part + 32;               // 2048
    short8v* packed = (short8v*)(part4 + 2048);  // 50KB, 16B-aligned offset

    k_pack<<<NFRAG, 64, 0, stream>>>(cW1, aW1, cW2, aW2, aW3, packed);
    k_mlp<<<(NTILE2 + 3) / 4, 256, 0, stream>>>(
        states, next_states, rewards, dones, actions, old_logp, packed,
        cb1, ab1, cb2, ab2, ab3, cW3, cb3, delta, coef, ratio, entb);
    k_gae_chunk<<<NCHUNK / 256, 256, 0, stream>>>(coef, delta, P, Q);
    k_gae_scan<<<1, 1024, 0, stream>>>(P, Q, carry);
    k_gae_apply<<<NCHUNK / 256, 256, 0, stream>>>(coef, delta, carry, adv, part);
    k_actor<<<NPART, 256, 0, stream>>>(adv, ratio, entb, part, part4);
    k_final<<<1, 1024, 0, stream>>>(part4, part, out);
}